// Round 21
// baseline (221.703 us; speedup 1.0000x reference)
//
#include <hip/hip_runtime.h>
#include <stdint.h>

#define TPB   256
#define D_DIM 4096
#define EPW   16       // elements per thread = D/TPB
#define NVEC  (EPW/4)  // 4
#define CAP   128      // candidate capacity per list (counts ~51/~65)
#define KSEL  16
#define THI0  2.5f     // top candidate threshold (true 16th ~3.2)
#define TLO0  0.02f    // bot candidate threshold (true 16th ~0.005)

// ws float offsets
#define WS_STDP 0
#define WS_MI   D_DIM
#define WS_SCAL (2*D_DIM)    // [0]=tau [1]=beta_up [2]=gamma [3]=beta_fam [4]=inv_e_norm
#define WS_GC   8200         // per-row gc scalar [rows]
#define WS_REC_F 24584       // u64 recs start (8B aligned)

typedef float vfloat4 __attribute__((ext_vector_type(4)));

__device__ __forceinline__ float fast_rcp(float v)  { return __builtin_amdgcn_rcpf(v); }
__device__ __forceinline__ float fast_exp2(float v) { return __builtin_amdgcn_exp2f(v); }

#define GELU_AN (-2.30220819f)   // -2c*log2e
#define GELU_BN (-0.10294331f)   // -2c*0.044715*log2e
#define TWO_LOG2E (2.8853900817779268f)
#define LOG2E     (1.4426950408889634f)

__device__ __forceinline__ float gelu_fast(float x) {
    float x2 = x * x;
    float s  = fmaf(x2, GELU_BN, GELU_AN);
    float nq = x * s;
    float ex = fast_exp2(nq);
    return x * fast_rcp(1.0f + ex);
}

__device__ __forceinline__ float tanh_fast_pm(float y2l) {
    float ex = fast_exp2(y2l);
    float r  = fast_rcp(1.0f + ex);
    return fmaf(-2.0f, r, 1.0f);
}

__device__ __forceinline__ float top_gate(float zz, float beta_up, float kg) {
    float g = fmaf(beta_up, tanh_fast_pm(zz * kg), 1.0f);
    return fminf(fmaxf(g, 0.1f), 8.0f);
}

// exact numpy z key: |z|-bits desc, tie -> lowest d; sign in LSB (inert for order)
__device__ __forceinline__ unsigned long long make_key_top(float zp, unsigned int d) {
    const unsigned int zb = __float_as_uint(zp);
    const unsigned int pb = zb & 0x7fffffffu;
    const unsigned int klo = 0xFFFFE000u | ((~d & 0xFFFu) << 1) | (zb >> 31);
    return ((unsigned long long)pb << 32) | klo;
}
__device__ __forceinline__ unsigned long long make_key_bot(float zp, unsigned int d) {
    const unsigned int zb = __float_as_uint(zp);
    const unsigned int pb = (zb & 0x7fffffffu) ^ 0x7fffffffu;
    const unsigned int klo = 0xFFFFE000u | ((~d & 0xFFFu) << 1) | (zb >> 31);
    return ((unsigned long long)pb << 32) | klo;
}

__device__ __forceinline__ unsigned int bf16_hi(float v) {
    unsigned int u = __float_as_uint(v);
    u = (u + 0x7FFFu + ((u >> 16) & 1u)) >> 16;   // round-to-nearest-even bf16
    return u & 0xFFFFu;
}

// ---- precompute: per-column stdp + packed bf16 (mu,inv) + scalars (1 block) ----
__global__ __launch_bounds__(256) void precomp(
    const float* __restrict__ em, const float* __restrict__ eq,
    const float* __restrict__ eo,
    const float* __restrict__ lt, const float* __restrict__ lb,
    const float* __restrict__ lg, const float* __restrict__ lf,
    float* __restrict__ ws)
{
    __shared__ float red[4];
    const int tid = threadIdx.x;
    unsigned int* wsu = (unsigned int*)ws;
    float e2 = 0.0f;
    for (int i = 0; i < D_DIM / 256; ++i) {
        const int d = i * 256 + tid;
        const float mu  = em[d];
        const float mu2 = __fmul_rn(mu, mu);
        float var = __fsub_rn(eq[d], mu2);
        var = fmaxf(var, 1e-4f);
        const float stdp = __fadd_rn(sqrtf(var), 1e-5f);  // bit-identical to numpy std+EPS
        ws[WS_STDP + d] = stdp;
        const float invv = 1.0f / stdp;
        wsu[WS_MI + d] = (bf16_hi(mu) << 16) | bf16_hi(invv);
        const float e = eo[d];
        e2 = fmaf(e, e, e2);
    }
    #pragma unroll
    for (int off = 32; off; off >>= 1) e2 += __shfl_xor(e2, off);
    if ((tid & 63) == 0) red[tid >> 6] = e2;
    __syncthreads();
    if (tid == 0) {
        const float t  = red[0] + red[1] + red[2] + red[3];
        const float en = sqrtf(t);
        ws[WS_SCAL + 0] = expf(lt[0]);
        ws[WS_SCAL + 1] = log1pf(expf(lb[0]));
        ws[WS_SCAL + 2] = log1pf(expf(lg[0]));
        ws[WS_SCAL + 3] = 1.0f / (1.0f + expf(-lf[0]));
        ws[WS_SCAL + 4] = 1.0f / fmaxf(en, 1e-12f);
    }
}

// ---- fused: grouped-load stream + select; nt-store; rank resolve -> recs ----
__global__ __launch_bounds__(TPB) void fused_gelu_gate(
    const float* __restrict__ x,
    const float* __restrict__ ema_mean,
    const float* __restrict__ ema_out,
    float* __restrict__ ws,
    unsigned long long* __restrict__ recs,
    float* __restrict__ out)
{
    __shared__ unsigned long long lists[2 * CAP];
    __shared__ float red[4][2];
    __shared__ unsigned int cnt[2];
    const int tid = threadIdx.x;
    const int ln  = tid & 63;
    const int wv  = tid >> 6;
    const long long base = (long long)blockIdx.x * D_DIM;

    if (tid < 2) cnt[tid] = 0u;
    __syncthreads();                                   // B1

    const float tau      = ws[WS_SCAL + 0];
    const float beta_up  = ws[WS_SCAL + 1];
    const float kg       = ws[WS_SCAL + 2] * TWO_LOG2E;
    const float beta_fam = ws[WS_SCAL + 3];
    const float inv_en   = ws[WS_SCAL + 4];
    const unsigned int* mip = (const unsigned int*)ws + WS_MI;

    float o_r[EPW];
    float s_o2 = 0.0f, s_dot = 0.0f;
    unsigned int maskT = 0u, maskB = 0u;

    // ---- pass 1: issue ALL 12 loads up front (max in-flight bytes), then compute ----
    float4 xv[NVEC];
    uint4  mv[NVEC];
    float4 ev[NVEC];
    #pragma unroll
    for (int i = 0; i < NVEC; ++i)
        xv[i] = *(const float4*)(x + base + (i * TPB + tid) * 4);
    #pragma unroll
    for (int i = 0; i < NVEC; ++i)
        mv[i] = *(const uint4*)(mip + (i * TPB + tid) * 4);
    #pragma unroll
    for (int i = 0; i < NVEC; ++i)
        ev[i] = *(const float4*)(ema_out + (i * TPB + tid) * 4);

    #pragma unroll
    for (int i = 0; i < NVEC; ++i) {
        const float xs[4] = {xv[i].x, xv[i].y, xv[i].z, xv[i].w};
        const unsigned int mis[4] = {mv[i].x, mv[i].y, mv[i].z, mv[i].w};
        const float es[4] = {ev[i].x, ev[i].y, ev[i].z, ev[i].w};
        #pragma unroll
        for (int j = 0; j < 4; ++j) {
            const int e = i * 4 + j;
            const float xx = xs[j];
            const float mu = __uint_as_float(mis[j] & 0xFFFF0000u);
            const float iv = __uint_as_float(mis[j] << 16);
            const float zz = (xx - mu) * iv;
            const float og = gelu_fast(xx);
            o_r[e] = og;
            s_o2  = fmaf(og, og, s_o2);
            s_dot = fmaf(og, es[j], s_dot);
            const float az = fabsf(zz);
            maskT |= (az >= THI0) ? (1u << e) : 0u;
            maskB |= (az <= TLO0) ? (1u << e) : 0u;
        }
    }

    // ---- collect: fully unrolled + predicated; x from REGISTERS (static index);
    //      inactive iterations skipped via execz, active ones pipeline ----
    #pragma unroll
    for (int i = 0; i < NVEC; ++i) {
        #pragma unroll
        for (int j = 0; j < 4; ++j) {
            const int e = i * 4 + j;
            if ((maskT | maskB) & (1u << e)) {
                const unsigned int d = (unsigned int)((i * TPB + tid) * 4 + j);
                const float xx   = (j == 0) ? xv[i].x : (j == 1) ? xv[i].y
                                 : (j == 2) ? xv[i].z : xv[i].w;   // static extract
                const float mu   = ema_mean[d];
                const float stdp = ws[WS_STDP + d];
                const float zp   = __fdiv_rn(__fsub_rn(xx, mu), stdp);
                if (maskT & (1u << e)) {
                    const unsigned int p = atomicAdd(&cnt[0], 1u);
                    if (p < CAP) lists[p] = make_key_top(zp, d);
                } else {
                    const unsigned int p = atomicAdd(&cnt[1], 1u);
                    if (p < CAP) lists[CAP + p] = make_key_bot(zp, d);
                }
            }
        }
    }

    // ---- block-reduce sums ----
    #pragma unroll
    for (int off = 32; off; off >>= 1) {
        s_o2  += __shfl_xor(s_o2, off);
        s_dot += __shfl_xor(s_dot, off);
    }
    if (ln == 0) { red[wv][0] = s_o2; red[wv][1] = s_dot; }
    __syncthreads();                                   // B2 (lists + red complete)

    float t_o2 = 0.0f, t_dot = 0.0f;
    #pragma unroll
    for (int w = 0; w < 4; ++w) { t_o2 += red[w][0]; t_dot += red[w][1]; }

    // ---- fallback (uniform branch; never taken for sane inputs) ----
    {
        unsigned int cT = cnt[0], cB = cnt[1];
        float thi = THI0, tlo = TLO0;
        int tries = 0;
        while ((cT < (unsigned)KSEL || cT > (unsigned)CAP ||
                cB < (unsigned)KSEL || cB > (unsigned)CAP) && tries < 20) {
            if (cT < (unsigned)KSEL) thi *= 0.5f; else if (cT > (unsigned)CAP) thi *= 1.5f;
            if (cB < (unsigned)KSEL) tlo *= 2.0f; else if (cB > (unsigned)CAP) tlo *= 0.6666f;
            __syncthreads();
            if (tid < 2) cnt[tid] = 0u;
            __syncthreads();
            for (int e = 0; e < EPW; ++e) {
                const unsigned int d = (unsigned int)(((e >> 2) * TPB + tid) * 4 + (e & 3));
                const float xx   = x[base + d];
                const float mu   = ema_mean[d];
                const float stdp = ws[WS_STDP + d];
                const float zp   = __fdiv_rn(__fsub_rn(xx, mu), stdp);
                const float az   = fabsf(zp);
                if (az >= thi) {
                    const unsigned int p = atomicAdd(&cnt[0], 1u);
                    if (p < CAP) lists[p] = make_key_top(zp, d);
                } else if (az <= tlo) {
                    const unsigned int p = atomicAdd(&cnt[1], 1u);
                    if (p < CAP) lists[CAP + p] = make_key_bot(zp, d);
                }
            }
            __syncthreads();
            cT = cnt[0]; cB = cnt[1];
            ++tries;
        }
    }

    // ---- cosine gate + bulk nt-store (fire-and-forget; winners fixed up later) ----
    const float on = sqrtf(t_o2);
    float cs = (t_dot * inv_en) / fmaxf(on, 1e-12f);
    cs = fminf(fmaxf(cs, -1.0f), 1.0f);
    const float gc = fast_exp2(-tau * cs * LOG2E);
    if (tid == 0) ws[WS_GC + blockIdx.x] = gc;

    #pragma unroll
    for (int i = 0; i < NVEC; ++i) {
        const int off = (i * TPB + tid) * 4;
        vfloat4 ov;
        ov.x = o_r[i * 4 + 0] * gc;
        ov.y = o_r[i * 4 + 1] * gc;
        ov.z = o_r[i * 4 + 2] * gc;
        ov.w = o_r[i * 4 + 3] * gc;
        __builtin_nontemporal_store(ov, (vfloat4*)(out + base + off));
    }

    // ---- rank-based winner selection (parallel, no serial tail) ----
    // threads [0,128): top list; threads [128,256): bot list
    {
        const unsigned int cT = min(cnt[0], (unsigned)CAP);
        const unsigned int cB = min(cnt[1], (unsigned)CAP);
        const int half = tid >> 7;                     // 0 = top, 1 = bot
        const unsigned int i = (unsigned int)(tid & 127);
        const unsigned int m = half ? cB : cT;
        if (i < m) {
            const unsigned long long* lp = &lists[half * CAP];
            const unsigned long long k_i = lp[i];
            unsigned int rank = 0;
            for (unsigned int j = 0; j < m; ++j)
                rank += (lp[j] > k_i) ? 1u : 0u;       // unique keys -> exact rank
            if (rank < (unsigned)KSEL) {
                const unsigned int klo = (unsigned int)(k_i & 0xffffffffu);
                const unsigned int d   = (~(klo >> 1)) & 0xFFFu;
                float g;
                if (half == 0) {
                    const unsigned int pb = (unsigned int)(k_i >> 32);
                    const float azf = __uint_as_float(pb);
                    const float zw  = (klo & 1u) ? -azf : azf;
                    g = top_gate(zw, beta_up, kg);
                } else {
                    g = beta_fam;
                }
                recs[(long long)blockIdx.x * 32 + half * KSEL + rank] =
                    ((unsigned long long)__float_as_uint(g) << 32) | d;
            }
        }
    }
}

// ---- fixup: rewrite the 32 winner elements per row ----
__global__ __launch_bounds__(256) void fixup(
    const float* __restrict__ x,
    const float* __restrict__ ws,
    const unsigned long long* __restrict__ recs,
    float* __restrict__ out)
{
    const int gid = blockIdx.x * 256 + threadIdx.x;    // one rec per thread
    const unsigned long long rec = recs[gid];
    const unsigned int d = (unsigned int)(rec & 0xFFFFu);
    if (d < (unsigned)D_DIM) {
        const int row = gid >> 5;
        const float gc = ws[WS_GC + row];
        const float g  = __uint_as_float((unsigned int)(rec >> 32));
        const long long idx = (long long)row * D_DIM + d;
        out[idx] = gelu_fast(x[idx]) * g * gc;
    }
}

extern "C" void kernel_launch(void* const* d_in, const int* in_sizes, int n_in,
                              void* d_out, int out_size, void* d_ws, size_t ws_size,
                              hipStream_t stream) {
    const float* x  = (const float*)d_in[0];
    const float* em = (const float*)d_in[1];
    const float* eq = (const float*)d_in[2];
    const float* eo = (const float*)d_in[3];
    const float* lt = (const float*)d_in[4];
    const float* lb = (const float*)d_in[5];
    const float* lg = (const float*)d_in[6];
    const float* lf = (const float*)d_in[7];
    float* o  = (float*)d_out;
    float* ws = (float*)d_ws;
    unsigned long long* recs = (unsigned long long*)(ws + WS_REC_F);
    const int rows = in_sizes[0] / D_DIM;
    precomp<<<dim3(1), dim3(256), 0, stream>>>(em, eq, eo, lt, lb, lg, lf, ws);
    fused_gelu_gate<<<dim3(rows), dim3(TPB), 0, stream>>>(x, em, eo, ws, recs, o);
    fixup<<<dim3(rows * 32 / 256), dim3(256), 0, stream>>>(x, ws, recs, o);
}

// Round 22
// 172.807 us; speedup vs baseline: 1.2830x; 1.2830x over previous
//
#include <hip/hip_runtime.h>
#include <stdint.h>

#define TPB   256
#define D_DIM 4096
#define EPW   16       // elements per thread = D/TPB
#define NVEC  (EPW/4)  // 4
#define CAP   128      // candidate capacity per list (counts ~51/~65)
#define KSEL  16
#define THI0  2.5f     // top candidate threshold (true 16th ~3.2)
#define TLO0  0.02f    // bot candidate threshold (true 16th ~0.005)

// ws float offsets
#define WS_MS   0            // float2 [mu, stdp] pairs: [0, 2*D)
#define WS_MI   (2*D_DIM)    // packed bf16 (mu<<16|inv): [2D, 3D)
#define WS_SCAL (3*D_DIM)    // [0]=tau [1]=beta_up [2]=gamma [3]=beta_fam [4]=inv_e_norm
#define WS_GC   (3*D_DIM+8)  // per-row gc scalar [rows]
#define WS_REC_F (3*D_DIM+8+16384)  // u64 recs start (byte off 114720, 8B aligned)

typedef float vfloat4 __attribute__((ext_vector_type(4)));

__device__ __forceinline__ float fast_rcp(float v)  { return __builtin_amdgcn_rcpf(v); }
__device__ __forceinline__ float fast_exp2(float v) { return __builtin_amdgcn_exp2f(v); }

#define GELU_AN (-2.30220819f)   // -2c*log2e
#define GELU_BN (-0.10294331f)   // -2c*0.044715*log2e
#define TWO_LOG2E (2.8853900817779268f)
#define LOG2E     (1.4426950408889634f)

__device__ __forceinline__ float gelu_fast(float x) {
    float x2 = x * x;
    float s  = fmaf(x2, GELU_BN, GELU_AN);
    float nq = x * s;
    float ex = fast_exp2(nq);
    return x * fast_rcp(1.0f + ex);
}

__device__ __forceinline__ float tanh_fast_pm(float y2l) {
    float ex = fast_exp2(y2l);
    float r  = fast_rcp(1.0f + ex);
    return fmaf(-2.0f, r, 1.0f);
}

__device__ __forceinline__ float top_gate(float zz, float beta_up, float kg) {
    float g = fmaf(beta_up, tanh_fast_pm(zz * kg), 1.0f);
    return fminf(fmaxf(g, 0.1f), 8.0f);
}

// exact numpy z key: |z|-bits desc, tie -> lowest d; sign in LSB (inert for order)
__device__ __forceinline__ unsigned long long make_key_top(float zp, unsigned int d) {
    const unsigned int zb = __float_as_uint(zp);
    const unsigned int pb = zb & 0x7fffffffu;
    const unsigned int klo = 0xFFFFE000u | ((~d & 0xFFFu) << 1) | (zb >> 31);
    return ((unsigned long long)pb << 32) | klo;
}
__device__ __forceinline__ unsigned long long make_key_bot(float zp, unsigned int d) {
    const unsigned int zb = __float_as_uint(zp);
    const unsigned int pb = (zb & 0x7fffffffu) ^ 0x7fffffffu;
    const unsigned int klo = 0xFFFFE000u | ((~d & 0xFFFu) << 1) | (zb >> 31);
    return ((unsigned long long)pb << 32) | klo;
}

__device__ __forceinline__ unsigned int bf16_hi(float v) {
    unsigned int u = __float_as_uint(v);
    u = (u + 0x7FFFu + ((u >> 16) & 1u)) >> 16;   // round-to-nearest-even bf16
    return u & 0xFFFFu;
}

// ---- precompute: (mu,stdp) pairs + packed bf16 (mu,inv) + scalars (1 block) ----
__global__ __launch_bounds__(256) void precomp(
    const float* __restrict__ em, const float* __restrict__ eq,
    const float* __restrict__ eo,
    const float* __restrict__ lt, const float* __restrict__ lb,
    const float* __restrict__ lg, const float* __restrict__ lf,
    float* __restrict__ ws)
{
    __shared__ float red[4];
    const int tid = threadIdx.x;
    unsigned int* wsu = (unsigned int*)ws;
    float e2 = 0.0f;
    for (int i = 0; i < D_DIM / 256; ++i) {
        const int d = i * 256 + tid;
        const float mu  = em[d];
        const float mu2 = __fmul_rn(mu, mu);
        float var = __fsub_rn(eq[d], mu2);
        var = fmaxf(var, 1e-4f);
        const float stdp = __fadd_rn(sqrtf(var), 1e-5f);  // bit-identical to numpy std+EPS
        float2 ms; ms.x = mu; ms.y = stdp;
        *(float2*)(ws + WS_MS + 2 * d) = ms;
        const float invv = 1.0f / stdp;
        wsu[WS_MI + d] = (bf16_hi(mu) << 16) | bf16_hi(invv);
        const float e = eo[d];
        e2 = fmaf(e, e, e2);
    }
    #pragma unroll
    for (int off = 32; off; off >>= 1) e2 += __shfl_xor(e2, off);
    if ((tid & 63) == 0) red[tid >> 6] = e2;
    __syncthreads();
    if (tid == 0) {
        const float t  = red[0] + red[1] + red[2] + red[3];
        const float en = sqrtf(t);
        ws[WS_SCAL + 0] = expf(lt[0]);
        ws[WS_SCAL + 1] = log1pf(expf(lb[0]));
        ws[WS_SCAL + 2] = log1pf(expf(lg[0]));
        ws[WS_SCAL + 3] = 1.0f / (1.0f + expf(-lf[0]));
        ws[WS_SCAL + 4] = 1.0f / fmaxf(en, 1e-12f);
    }
}

// ---- fused: grouped-load stream + select; nt-store; rank resolve -> recs ----
__global__ __launch_bounds__(TPB) void fused_gelu_gate(
    const float* __restrict__ x,
    const float* __restrict__ ema_out,
    float* __restrict__ ws,
    unsigned long long* __restrict__ recs,
    float* __restrict__ out)
{
    __shared__ unsigned long long lists[2 * CAP];
    __shared__ float red[4][2];
    __shared__ unsigned int cnt[2];
    const int tid = threadIdx.x;
    const int ln  = tid & 63;
    const int wv  = tid >> 6;
    const long long base = (long long)blockIdx.x * D_DIM;

    if (tid < 2) cnt[tid] = 0u;
    __syncthreads();                                   // B1

    const float tau      = ws[WS_SCAL + 0];
    const float beta_up  = ws[WS_SCAL + 1];
    const float kg       = ws[WS_SCAL + 2] * TWO_LOG2E;
    const float beta_fam = ws[WS_SCAL + 3];
    const float inv_en   = ws[WS_SCAL + 4];
    const unsigned int* mip = (const unsigned int*)ws + WS_MI;

    float o_r[EPW];
    float s_o2 = 0.0f, s_dot = 0.0f;
    unsigned int maskT = 0u, maskB = 0u;

    // ---- pass 1: issue ALL 12 loads up front (max in-flight bytes), then compute ----
    float4 xv[NVEC];
    uint4  mv[NVEC];
    float4 ev[NVEC];
    #pragma unroll
    for (int i = 0; i < NVEC; ++i)
        xv[i] = *(const float4*)(x + base + (i * TPB + tid) * 4);
    #pragma unroll
    for (int i = 0; i < NVEC; ++i)
        mv[i] = *(const uint4*)(mip + (i * TPB + tid) * 4);
    #pragma unroll
    for (int i = 0; i < NVEC; ++i)
        ev[i] = *(const float4*)(ema_out + (i * TPB + tid) * 4);

    #pragma unroll
    for (int i = 0; i < NVEC; ++i) {
        const float xs[4] = {xv[i].x, xv[i].y, xv[i].z, xv[i].w};
        const unsigned int mis[4] = {mv[i].x, mv[i].y, mv[i].z, mv[i].w};
        const float es[4] = {ev[i].x, ev[i].y, ev[i].z, ev[i].w};
        #pragma unroll
        for (int j = 0; j < 4; ++j) {
            const int e = i * 4 + j;
            const float xx = xs[j];
            const float mu = __uint_as_float(mis[j] & 0xFFFF0000u);
            const float iv = __uint_as_float(mis[j] << 16);
            const float zz = (xx - mu) * iv;
            const float og = gelu_fast(xx);
            o_r[e] = og;
            s_o2  = fmaf(og, og, s_o2);
            s_dot = fmaf(og, es[j], s_dot);
            const float az = fabsf(zz);
            maskT |= (az >= THI0) ? (1u << e) : 0u;
            maskB |= (az <= TLO0) ? (1u << e) : 0u;
        }
    }

    // ---- deferred candidate collect (rare): exact z via scalar reload + packed pair ----
    {
        unsigned int mT = maskT;
        while (mT) {
            const int e = __ffs(mT) - 1; mT &= mT - 1u;
            const unsigned int d = (unsigned int)(((e >> 2) * TPB + tid) * 4 + (e & 3));
            const float xx   = x[base + d];
            const float2 ms = *(const float2*)(ws + WS_MS + 2 * d);
            const float zp   = __fdiv_rn(__fsub_rn(xx, ms.x), ms.y);
            const unsigned int p = atomicAdd(&cnt[0], 1u);
            if (p < CAP) lists[p] = make_key_top(zp, d);
        }
        unsigned int mB = maskB;
        while (mB) {
            const int e = __ffs(mB) - 1; mB &= mB - 1u;
            const unsigned int d = (unsigned int)(((e >> 2) * TPB + tid) * 4 + (e & 3));
            const float xx   = x[base + d];
            const float2 ms = *(const float2*)(ws + WS_MS + 2 * d);
            const float zp   = __fdiv_rn(__fsub_rn(xx, ms.x), ms.y);
            const unsigned int p = atomicAdd(&cnt[1], 1u);
            if (p < CAP) lists[CAP + p] = make_key_bot(zp, d);
        }
    }

    // ---- block-reduce sums ----
    #pragma unroll
    for (int off = 32; off; off >>= 1) {
        s_o2  += __shfl_xor(s_o2, off);
        s_dot += __shfl_xor(s_dot, off);
    }
    if (ln == 0) { red[wv][0] = s_o2; red[wv][1] = s_dot; }
    __syncthreads();                                   // B2 (lists + red complete)

    float t_o2 = 0.0f, t_dot = 0.0f;
    #pragma unroll
    for (int w = 0; w < 4; ++w) { t_o2 += red[w][0]; t_dot += red[w][1]; }

    // ---- fallback (uniform branch; never taken for sane inputs) ----
    {
        unsigned int cT = cnt[0], cB = cnt[1];
        float thi = THI0, tlo = TLO0;
        int tries = 0;
        while ((cT < (unsigned)KSEL || cT > (unsigned)CAP ||
                cB < (unsigned)KSEL || cB > (unsigned)CAP) && tries < 20) {
            if (cT < (unsigned)KSEL) thi *= 0.5f; else if (cT > (unsigned)CAP) thi *= 1.5f;
            if (cB < (unsigned)KSEL) tlo *= 2.0f; else if (cB > (unsigned)CAP) tlo *= 0.6666f;
            __syncthreads();
            if (tid < 2) cnt[tid] = 0u;
            __syncthreads();
            for (int e = 0; e < EPW; ++e) {
                const unsigned int d = (unsigned int)(((e >> 2) * TPB + tid) * 4 + (e & 3));
                const float xx   = x[base + d];
                const float2 ms = *(const float2*)(ws + WS_MS + 2 * d);
                const float zp   = __fdiv_rn(__fsub_rn(xx, ms.x), ms.y);
                const float az   = fabsf(zp);
                if (az >= thi) {
                    const unsigned int p = atomicAdd(&cnt[0], 1u);
                    if (p < CAP) lists[p] = make_key_top(zp, d);
                } else if (az <= tlo) {
                    const unsigned int p = atomicAdd(&cnt[1], 1u);
                    if (p < CAP) lists[CAP + p] = make_key_bot(zp, d);
                }
            }
            __syncthreads();
            cT = cnt[0]; cB = cnt[1];
            ++tries;
        }
    }

    // ---- cosine gate + bulk nt-store (fire-and-forget; winners fixed up later) ----
    const float on = sqrtf(t_o2);
    float cs = (t_dot * inv_en) / fmaxf(on, 1e-12f);
    cs = fminf(fmaxf(cs, -1.0f), 1.0f);
    const float gc = fast_exp2(-tau * cs * LOG2E);
    if (tid == 0) ws[WS_GC + blockIdx.x] = gc;

    #pragma unroll
    for (int i = 0; i < NVEC; ++i) {
        const int off = (i * TPB + tid) * 4;
        vfloat4 ov;
        ov.x = o_r[i * 4 + 0] * gc;
        ov.y = o_r[i * 4 + 1] * gc;
        ov.z = o_r[i * 4 + 2] * gc;
        ov.w = o_r[i * 4 + 3] * gc;
        __builtin_nontemporal_store(ov, (vfloat4*)(out + base + off));
    }

    // ---- rank-based winner selection (parallel, no serial tail) ----
    // threads [0,128): top list; threads [128,256): bot list
    {
        const unsigned int cT = min(cnt[0], (unsigned)CAP);
        const unsigned int cB = min(cnt[1], (unsigned)CAP);
        const int half = tid >> 7;                     // 0 = top, 1 = bot
        const unsigned int i = (unsigned int)(tid & 127);
        const unsigned int m = half ? cB : cT;
        if (i < m) {
            const unsigned long long* lp = &lists[half * CAP];
            const unsigned long long k_i = lp[i];
            unsigned int rank = 0;
            for (unsigned int j = 0; j < m; ++j)
                rank += (lp[j] > k_i) ? 1u : 0u;       // unique keys -> exact rank
            if (rank < (unsigned)KSEL) {
                const unsigned int klo = (unsigned int)(k_i & 0xffffffffu);
                const unsigned int d   = (~(klo >> 1)) & 0xFFFu;
                float g;
                if (half == 0) {
                    const unsigned int pb = (unsigned int)(k_i >> 32);
                    const float azf = __uint_as_float(pb);
                    const float zw  = (klo & 1u) ? -azf : azf;
                    g = top_gate(zw, beta_up, kg);
                } else {
                    g = beta_fam;
                }
                recs[(long long)blockIdx.x * 32 + half * KSEL + rank] =
                    ((unsigned long long)__float_as_uint(g) << 32) | d;
            }
        }
    }
}

// ---- fixup: rewrite the 32 winner elements per row ----
__global__ __launch_bounds__(256) void fixup(
    const float* __restrict__ x,
    const float* __restrict__ ws,
    const unsigned long long* __restrict__ recs,
    float* __restrict__ out)
{
    const int gid = blockIdx.x * 256 + threadIdx.x;    // one rec per thread
    const unsigned long long rec = recs[gid];
    const unsigned int d = (unsigned int)(rec & 0xFFFFu);
    if (d < (unsigned)D_DIM) {
        const int row = gid >> 5;
        const float gc = ws[WS_GC + row];
        const float g  = __uint_as_float((unsigned int)(rec >> 32));
        const long long idx = (long long)row * D_DIM + d;
        out[idx] = gelu_fast(x[idx]) * g * gc;
    }
}

extern "C" void kernel_launch(void* const* d_in, const int* in_sizes, int n_in,
                              void* d_out, int out_size, void* d_ws, size_t ws_size,
                              hipStream_t stream) {
    const float* x  = (const float*)d_in[0];
    const float* em = (const float*)d_in[1];
    const float* eq = (const float*)d_in[2];
    const float* eo = (const float*)d_in[3];
    const float* lt = (const float*)d_in[4];
    const float* lb = (const float*)d_in[5];
    const float* lg = (const float*)d_in[6];
    const float* lf = (const float*)d_in[7];
    float* o  = (float*)d_out;
    float* ws = (float*)d_ws;
    unsigned long long* recs = (unsigned long long*)(ws + WS_REC_F);
    const int rows = in_sizes[0] / D_DIM;
    precomp<<<dim3(1), dim3(256), 0, stream>>>(em, eq, eo, lt, lb, lg, lf, ws);
    fused_gelu_gate<<<dim3(rows), dim3(TPB), 0, stream>>>(x, eo, ws, recs, o);
    fixup<<<dim3(rows * 32 / 256), dim3(256), 0, stream>>>(x, ws, recs, o);
}